// Round 16
// baseline (80.643 us; speedup 1.0000x reference)
//
#include <hip/hip_runtime.h>

typedef __attribute__((ext_vector_type(8))) short bf16x8;
typedef __attribute__((ext_vector_type(4))) float f32x4;

#define M_TOT 6400   // 80*80 flattened spatial positions
#define C_TOT 256    // channels (K of the main GEMM)
#define BM 128
#define BN 128
#define BK 32
#define NTILE 50     // 6400 / 128

#define VMCNT0 asm volatile("s_waitcnt vmcnt(0)" ::: "memory")
#define VMCNT2 asm volatile("s_waitcnt vmcnt(2)" ::: "memory")
#define VMCNT4 asm volatile("s_waitcnt vmcnt(4)" ::: "memory")
#define SBAR   __builtin_amdgcn_s_barrier()

// f32 -> bf16 round-to-nearest-even
__device__ __forceinline__ short f2bf(float f) {
    unsigned u = __float_as_uint(f);
    u = (u + 0x7fffu + ((u >> 16) & 1u)) >> 16;
    return (short)u;
}
__device__ __forceinline__ float bf2f(short s) {
    return __uint_as_float(((unsigned)(unsigned short)s) << 16);
}

// async global->LDS, 16B per lane; LDS dst is wave-uniform base + lane*16
__device__ __forceinline__ void gload16(const short* g, short* l) {
    __builtin_amdgcn_global_load_lds(
        (const __attribute__((address_space(1))) void*)g,
        (__attribute__((address_space(3))) void*)l, 16, 0, 0);
}

// ---------------- fused prep: A->Ab, B->(Bb,Bt), zero P ----------------

__global__ __launch_bounds__(256) void prep(const float* __restrict__ A,
                                            const float* __restrict__ Bm,
                                            short* __restrict__ Ab,
                                            short* __restrict__ Bb,
                                            short* __restrict__ Bt,
                                            float* __restrict__ P)
{
    __shared__ __align__(16) short Lb[64][72];
    const int bid = blockIdx.x;
    const int t   = threadIdx.x;

    if (bid < 400) {
        const int n0 = (bid % 100) * 64;
        const int c0 = (bid / 100) * 64;
        const int r  = t >> 2;
        const int cb = (t & 3) * 16;

        const float4* src = reinterpret_cast<const float4*>(
            Bm + (size_t)(n0 + r) * C_TOT + c0 + cb);
        const float4 v0 = src[0], v1 = src[1], v2 = src[2], v3 = src[3];
        bf16x8 w0, w1;
        w0[0]=f2bf(v0.x); w0[1]=f2bf(v0.y); w0[2]=f2bf(v0.z); w0[3]=f2bf(v0.w);
        w0[4]=f2bf(v1.x); w0[5]=f2bf(v1.y); w0[6]=f2bf(v1.z); w0[7]=f2bf(v1.w);
        w1[0]=f2bf(v2.x); w1[1]=f2bf(v2.y); w1[2]=f2bf(v2.z); w1[3]=f2bf(v2.w);
        w1[4]=f2bf(v3.x); w1[5]=f2bf(v3.y); w1[6]=f2bf(v3.z); w1[7]=f2bf(v3.w);
        *reinterpret_cast<bf16x8*>(&Lb[r][cb])     = w0;
        *reinterpret_cast<bf16x8*>(&Lb[r][cb + 8]) = w1;
        short* brow = Bb + (size_t)(n0 + r) * C_TOT + c0 + cb;
        *reinterpret_cast<bf16x8*>(brow)     = w0;
        *reinterpret_cast<bf16x8*>(brow + 8) = w1;
        __syncthreads();

        #pragma unroll
        for (int p = 0; p < 2; ++p) {
            const int q = t + p * 256;
            const int c = q >> 3;
            const int h = q & 7;
            bf16x8 w;
            #pragma unroll
            for (int j = 0; j < 8; ++j) w[j] = Lb[h * 8 + j][c];
            *reinterpret_cast<bf16x8*>(&Bt[(size_t)(c0 + c) * M_TOT + n0 + h * 8]) = w;
        }
    } else {
        const int aid = bid - 400;   // 0..99
        if (aid == 0)
            for (int j = t; j < M_TOT; j += 256) P[j] = 0.0f;
        const int base = aid * 2048;
        #pragma unroll
        for (int it = 0; it < 8; ++it) {
            const int i = base + it * 256 + t;
            const float4 v0 = reinterpret_cast<const float4*>(A + (size_t)i * 8)[0];
            const float4 v1 = reinterpret_cast<const float4*>(A + (size_t)i * 8)[1];
            bf16x8 w;
            w[0]=f2bf(v0.x); w[1]=f2bf(v0.y); w[2]=f2bf(v0.z); w[3]=f2bf(v0.w);
            w[4]=f2bf(v1.x); w[5]=f2bf(v1.y); w[6]=f2bf(v1.z); w[7]=f2bf(v1.w);
            *reinterpret_cast<bf16x8*>(Ab + (size_t)i * 8) = w;
        }
    }
}

// ------- 4-wave staged 128x128 tile machinery (fallback paths) -------

__device__ __forceinline__ void stage_tiles_g(const short* __restrict__ A,
                                              const short* __restrict__ B,
                                              int m0, int n0, int k0,
                                              int lda, int ldb,
                                              short* As, short* Bs,
                                              int wave, int lane)
{
    #pragma unroll
    for (int t = 0; t < 2; ++t) {
        const int c  = (wave * 2 + t) * 64 + lane;
        const int r  = c >> 2;
        const int g  = c & 3;
        const int sg = g ^ ((r >> 1) & 3);
        gload16(A + (size_t)(m0 + r) * lda + k0 + sg * 8, As + (wave * 2 + t) * 512);
        gload16(B + (size_t)(n0 + r) * ldb + k0 + sg * 8, Bs + (wave * 2 + t) * 512);
    }
}

template<int KSTEPS>
__device__ __forceinline__ void gemm_tile_g(const short* __restrict__ A,
                                            const short* __restrict__ B,
                                            int m0, int n0, int kbase,
                                            int lda, int ldb, int tid,
                                            short (*Sm)[2][4096],
                                            f32x4 acc[4][4])
{
    const int lane = tid & 63;
    const int wave = tid >> 6;
    const int rl   = lane & 15;
    const int g_rd = lane >> 4;
    const int wr   = wave >> 1;
    const int wc   = wave & 1;

    stage_tiles_g(A, B, m0, n0, kbase, lda, ldb, &Sm[0][0][0], &Sm[0][1][0], wave, lane);
    if (KSTEPS > 1)
        stage_tiles_g(A, B, m0, n0, kbase + BK, lda, ldb,
                      &Sm[1][0][0], &Sm[1][1][0], wave, lane);
    if (KSTEPS > 1) { VMCNT4; } else { VMCNT0; }
    SBAR;

    #pragma unroll
    for (int kt = 0; kt < KSTEPS; ++kt) {
        const int cur = kt % 3;
        if (kt + 2 < KSTEPS)
            stage_tiles_g(A, B, m0, n0, kbase + (kt + 2) * BK, lda, ldb,
                          &Sm[(kt + 2) % 3][0][0], &Sm[(kt + 2) % 3][1][0], wave, lane);

        bf16x8 af[4], bfr[4];
        #pragma unroll
        for (int mi = 0; mi < 4; ++mi) {
            const int r  = wr * 64 + mi * 16 + rl;
            const int sg = g_rd ^ ((r >> 1) & 3);
            af[mi] = *reinterpret_cast<const bf16x8*>(&Sm[cur][0][r * BK + sg * 8]);
        }
        #pragma unroll
        for (int ni = 0; ni < 4; ++ni) {
            const int r  = wc * 64 + ni * 16 + rl;
            const int sg = g_rd ^ ((r >> 1) & 3);
            bfr[ni] = *reinterpret_cast<const bf16x8*>(&Sm[cur][1][r * BK + sg * 8]);
        }
        __builtin_amdgcn_s_setprio(1);
        #pragma unroll
        for (int mi = 0; mi < 4; ++mi)
            #pragma unroll
            for (int ni = 0; ni < 4; ++ni)
                acc[mi][ni] = __builtin_amdgcn_mfma_f32_16x16x32_bf16(
                    af[mi], bfr[ni], acc[mi][ni], 0, 0, 0);
        __builtin_amdgcn_s_setprio(0);

        if (kt + 1 < KSTEPS) {
            if (kt + 2 < KSTEPS) { VMCNT4; } else { VMCNT0; }
            SBAR;
        }
    }
}

// ------- 8-wave (512-thread) staged 128x128 tile: per-wave 64x32, acc[4][2] -------
// Stage = 2 gload16/thread; counted wait vmcnt(2); LDS 16 KB/buf x 3 = 48 KB.

__device__ __forceinline__ void stage_g512(const short* __restrict__ A,
                                           const short* __restrict__ B,
                                           int m0, int n0, int k0,
                                           int lda, int ldb,
                                           short* buf, int wave, int lane)
{
    const int c  = wave * 64 + lane;   // 0..511
    const int r  = c >> 2;              // 0..127
    const int g  = c & 3;
    const int sg = g ^ ((r >> 1) & 3);
    gload16(A + (size_t)(m0 + r) * lda + k0 + sg * 8, buf + wave * 512);
    gload16(B + (size_t)(n0 + r) * ldb + k0 + sg * 8, buf + 4096 + wave * 512);
}

template<int KSTEPS>
__device__ __forceinline__ void gemm_tile_512g(const short* __restrict__ A,
                                               const short* __restrict__ B,
                                               int m0, int n0, int kbase,
                                               int lda, int ldb, int tid,
                                               short (*Sm)[8192],
                                               f32x4 acc[4][2])
{
    const int lane = tid & 63;
    const int wave = tid >> 6;        // 0..7
    const int rl   = lane & 15;
    const int g_rd = lane >> 4;
    const int wr   = wave >> 2;       // 0..1
    const int wc   = wave & 3;        // 0..3

    stage_g512(A, B, m0, n0, kbase, lda, ldb, Sm[0], wave, lane);
    if (KSTEPS > 1)
        stage_g512(A, B, m0, n0, kbase + BK, lda, ldb, Sm[1], wave, lane);
    if (KSTEPS > 1) { VMCNT2; } else { VMCNT0; }
    SBAR;

    #pragma unroll
    for (int kt = 0; kt < KSTEPS; ++kt) {
        const int cur = kt % 3;
        if (kt + 2 < KSTEPS)
            stage_g512(A, B, m0, n0, kbase + (kt + 2) * BK, lda, ldb,
                       Sm[(kt + 2) % 3], wave, lane);

        bf16x8 af[4], bfr[2];
        #pragma unroll
        for (int mi = 0; mi < 4; ++mi) {
            const int rr = wr * 64 + mi * 16 + rl;
            const int sg = g_rd ^ ((rr >> 1) & 3);
            af[mi] = *reinterpret_cast<const bf16x8*>(&Sm[cur][rr * BK + sg * 8]);
        }
        #pragma unroll
        for (int ni = 0; ni < 2; ++ni) {
            const int rr = wc * 32 + ni * 16 + rl;
            const int sg = g_rd ^ ((rr >> 1) & 3);
            bfr[ni] = *reinterpret_cast<const bf16x8*>(&Sm[cur][4096 + rr * BK + sg * 8]);
        }
        __builtin_amdgcn_s_setprio(1);
        #pragma unroll
        for (int mi = 0; mi < 4; ++mi)
            #pragma unroll
            for (int ni = 0; ni < 2; ++ni)
                acc[mi][ni] = __builtin_amdgcn_mfma_f32_16x16x32_bf16(
                    af[mi], bfr[ni], acc[mi][ni], 0, 0, 0);
        __builtin_amdgcn_s_setprio(0);

        if (kt + 1 < KSTEPS) {
            if (kt + 2 < KSTEPS) { VMCNT2; } else { VMCNT0; }
            SBAR;
        }
    }
}

// ---------------- Gram path (512-thread / 8-wave) ----------------

template<int STEPS>
__global__ __launch_bounds__(512, 4) void gemm_G(const short* __restrict__ Bt,
                                                 float* __restrict__ Gp)
{
    __shared__ __align__(16) short Sm[3][8192];   // 48 KB
    const int tid = threadIdx.x;
    const int m0 = blockIdx.y * BM, n0 = blockIdx.x * BN;
    const int z  = blockIdx.z;
    f32x4 acc[4][2] = {};
    gemm_tile_512g<STEPS>(Bt, Bt, m0, n0, z * (STEPS * BK),
                          M_TOT, M_TOT, tid, Sm, acc);

    float* dst = Gp + (size_t)z * (C_TOT * C_TOT);
    const int lane = tid & 63, rl = lane & 15;
    const int wave = tid >> 6, wr = wave >> 2, wc = wave & 3;
    #pragma unroll
    for (int mi = 0; mi < 4; ++mi)
        #pragma unroll
        for (int i = 0; i < 4; ++i) {
            const int m = m0 + wr * 64 + mi * 16 + (lane >> 4) * 4 + i;
            #pragma unroll
            for (int ni = 0; ni < 2; ++ni)
                dst[m * C_TOT + n0 + wc * 32 + ni * 16 + rl] = acc[mi][ni][i];
        }
}

__global__ __launch_bounds__(256) void g_reduce(const float* __restrict__ Gp,
                                                short* __restrict__ Gb,
                                                int nchunks)
{
    const int i4 = blockIdx.x * 256 + threadIdx.x;
    float4 s = make_float4(0.f, 0.f, 0.f, 0.f);
    for (int z = 0; z < nchunks; ++z) {
        const float4 v = reinterpret_cast<const float4*>(
            Gp + (size_t)z * (C_TOT * C_TOT))[i4];
        s.x += v.x; s.y += v.y; s.z += v.z; s.w += v.w;
    }
    short4 o;
    o.x = f2bf(s.x); o.y = f2bf(s.y); o.z = f2bf(s.z); o.w = f2bf(s.w);
    reinterpret_cast<short4*>(Gb)[i4] = o;
}

// P[m] += sum over quadrant (ci, cj); 512-thread / 8-wave
__global__ __launch_bounds__(512, 4) void penalty_q(const short* __restrict__ Ab,
                                                    const short* __restrict__ Gb,
                                                    float* __restrict__ P)
{
    __shared__ __align__(16) short Sm[3][8192];
    const int tid = threadIdx.x;
    const int m0 = blockIdx.x * BM;
    const int ci = blockIdx.y & 1, cj = blockIdx.y >> 1;
    const int lane = tid & 63, rl = lane & 15;
    const int wave = tid >> 6, wr = wave >> 2, wc = wave & 3;

    f32x4 acc[4][2] = {};
    gemm_tile_512g<4>(Ab, Gb + (size_t)(cj * BM) * C_TOT, m0, 0, ci * BM,
                      C_TOT, C_TOT, tid, Sm, acc);

    #pragma unroll
    for (int mi = 0; mi < 4; ++mi)
        #pragma unroll
        for (int i = 0; i < 4; ++i) {
            const int m = m0 + wr * 64 + mi * 16 + (lane >> 4) * 4 + i;
            float s = 0.0f;
            #pragma unroll
            for (int ni = 0; ni < 2; ++ni) {
                const int cp = cj * BM + wc * 32 + ni * 16 + rl;
                s += acc[mi][ni][i] * bf2f(Ab[(size_t)m * C_TOT + cp]);
            }
            s += __shfl_xor(s, 1);
            s += __shfl_xor(s, 2);
            s += __shfl_xor(s, 4);
            s += __shfl_xor(s, 8);
            if (rl == 0) atomicAdd(&P[m], s);
        }
}

// ------- output GEMM: 128x128 tile, 512 threads, 2-BUFFER, 8 waves/SIMD -------
// LDS 32 KB -> 4 blocks/CU (thread-capped); __launch_bounds__(512,8) caps VGPR
// at 64 -> 32 waves/CU = 8 waves/SIMD (hardware max). The 2-phase vmcnt(0)
// drain per K-step is the price; bet: max TLP hides it (m114, rounds 12/15).

__global__ __launch_bounds__(512, 8) void gemm_out(const short* __restrict__ Ab,
                                                   const short* __restrict__ Bb,
                                                   const float* __restrict__ P,
                                                   float* __restrict__ out)
{
    __shared__ __align__(16) short Sm[2][8192];   // 32 KB
    const int tid = threadIdx.x;
    const int lane = tid & 63, rl = lane & 15;
    const int g_rd = lane >> 4;
    const int wave = tid >> 6;            // 0..7
    const int wr   = wave >> 2;           // 0..1  (m half)
    const int wc   = wave & 3;            // 0..3  (n quarter)

    // bijective chunked XCD swizzle (m204): 2500 blocks, 8 XCDs (q=312, r=4)
    const int nwg = NTILE * NTILE, q = nwg >> 3, r = nwg & 7;
    const int orig = blockIdx.x;
    const int xcd = orig & 7, idx = orig >> 3;
    const int wg = (xcd < r ? xcd * (q + 1) : r * (q + 1) + (xcd - r) * q) + idx;
    const int m0 = (wg / NTILE) * BM;
    const int n0 = (wg % NTILE) * BN;

    f32x4 acc[4][2] = {};

    stage_g512(Ab, Bb, m0, n0, 0, C_TOT, C_TOT, Sm[0], wave, lane);
    VMCNT0; SBAR;

    #pragma unroll
    for (int kt = 0; kt < 8; ++kt) {
        const int cur = kt & 1;
        if (kt + 1 < 8)
            stage_g512(Ab, Bb, m0, n0, (kt + 1) * BK, C_TOT, C_TOT,
                       Sm[cur ^ 1], wave, lane);

        // B fragments once per K-step; A fragments loaded per-mi to keep
        // live ranges short (target: fit the 64-VGPR cap without spill).
        bf16x8 bfr[2];
        #pragma unroll
        for (int ni = 0; ni < 2; ++ni) {
            const int rr = wc * 32 + ni * 16 + rl;
            const int sg = g_rd ^ ((rr >> 1) & 3);
            bfr[ni] = *reinterpret_cast<const bf16x8*>(&Sm[cur][4096 + rr * BK + sg * 8]);
        }
        __builtin_amdgcn_s_setprio(1);
        #pragma unroll
        for (int mi = 0; mi < 4; ++mi) {
            const int rr = wr * 64 + mi * 16 + rl;
            const int sg = g_rd ^ ((rr >> 1) & 3);
            const bf16x8 af = *reinterpret_cast<const bf16x8*>(&Sm[cur][rr * BK + sg * 8]);
            #pragma unroll
            for (int ni = 0; ni < 2; ++ni)
                acc[mi][ni] = __builtin_amdgcn_mfma_f32_16x16x32_bf16(
                    af, bfr[ni], acc[mi][ni], 0, 0, 0);
        }
        __builtin_amdgcn_s_setprio(0);

        if (kt + 1 < 8) { VMCNT0; SBAR; }
    }

    float rs[2];
    #pragma unroll
    for (int ni = 0; ni < 2; ++ni)
        rs[ni] = rsqrtf(P[n0 + wc * 32 + ni * 16 + rl]);

    SBAR;   // all waves done reading Sm before epilogue scratch reuse

    // wave-private 16x36 f32 scratch (8 waves x 2304 B = 18 KB, aliased on Sm)
    float* Es = reinterpret_cast<float*>(Sm) + wave * 576;
    #pragma unroll
    for (int mi = 0; mi < 4; ++mi) {
        #pragma unroll
        for (int ni = 0; ni < 2; ++ni)
            #pragma unroll
            for (int i = 0; i < 4; ++i)
                Es[((lane >> 4) * 4 + i) * 36 + ni * 16 + rl] = acc[mi][ni][i] * rs[ni];
        #pragma unroll
        for (int it = 0; it < 2; ++it) {
            const int f   = it * 64 + lane;   // 0..127
            const int row = f >> 3;           // 0..15
            const int c4  = f & 7;            // float4 column 0..7
            const f32x4 v = *reinterpret_cast<const f32x4*>(&Es[row * 36 + c4 * 4]);
            const int m = m0 + wr * 64 + mi * 16 + row;
            __builtin_nontemporal_store(v, reinterpret_cast<f32x4*>(
                &out[(size_t)m * M_TOT + n0 + wc * 32 + c4 * 4]));
        }
    }
}

// ---------------- mid fallback: two-GEMM (128^2, staged, 4-wave) ----------------

__global__ __launch_bounds__(256) void convert_ab(const float* __restrict__ A,
                                                  const float* __restrict__ Bm,
                                                  short* __restrict__ Ab,
                                                  short* __restrict__ Bb)
{
    const int n8 = M_TOT * C_TOT / 8;
    for (int i = blockIdx.x * blockDim.x + threadIdx.x; i < 2 * n8;
         i += gridDim.x * blockDim.x) {
        const float* s = (i < n8) ? (A + (size_t)i * 8) : (Bm + (size_t)(i - n8) * 8);
        short* d       = (i < n8) ? (Ab + (size_t)i * 8) : (Bb + (size_t)(i - n8) * 8);
        const float4 v0 = reinterpret_cast<const float4*>(s)[0];
        const float4 v1 = reinterpret_cast<const float4*>(s)[1];
        bf16x8 w;
        w[0]=f2bf(v0.x); w[1]=f2bf(v0.y); w[2]=f2bf(v0.z); w[3]=f2bf(v0.w);
        w[4]=f2bf(v1.x); w[5]=f2bf(v1.y); w[6]=f2bf(v1.z); w[7]=f2bf(v1.w);
        *reinterpret_cast<bf16x8*>(d) = w;
    }
}

__global__ __launch_bounds__(256) void gemm_penalty(const short* __restrict__ Ab,
                                                    const short* __restrict__ Bb,
                                                    float* __restrict__ P)
{
    __shared__ __align__(16) short Sm[3][2][4096];
    const int tid = threadIdx.x;
    const int m0 = blockIdx.y * BM, n0 = blockIdx.x * BN;
    f32x4 acc[4][4] = {};
    gemm_tile_g<8>(Ab, Bb, m0, n0, 0, C_TOT, C_TOT, tid, Sm, acc);

    const int lane = tid & 63, rl = lane & 15;
    const int wave = tid >> 6, wr = wave >> 1;
    #pragma unroll
    for (int mi = 0; mi < 4; ++mi) {
        #pragma unroll
        for (int i = 0; i < 4; ++i) {
            const int m = m0 + wr * 64 + mi * 16 + (lane >> 4) * 4 + i;
            float s = 0.0f;
            #pragma unroll
            for (int ni = 0; ni < 4; ++ni) {
                const float v = acc[mi][ni][i];
                s += v * v;
            }
            s += __shfl_xor(s, 1);
            s += __shfl_xor(s, 2);
            s += __shfl_xor(s, 4);
            s += __shfl_xor(s, 8);
            if (rl == 0) atomicAdd(&P[m], s);
        }
    }
}

__global__ __launch_bounds__(256) void gemm_out_plain(const short* __restrict__ Ab,
                                                      const short* __restrict__ Bb,
                                                      const float* __restrict__ P,
                                                      float* __restrict__ out)
{
    __shared__ __align__(16) short Sm[3][2][4096];
    const int tid = threadIdx.x;
    const int lane = tid & 63, rl = lane & 15;
    const int wave = tid >> 6, wr = wave >> 1, wc = wave & 1;
    const int m0 = blockIdx.y * BM, n0 = blockIdx.x * BN;

    f32x4 acc[4][4] = {};
    gemm_tile_g<8>(Ab, Bb, m0, n0, 0, C_TOT, C_TOT, tid, Sm, acc);

    float rs[4];
    #pragma unroll
    for (int ni = 0; ni < 4; ++ni)
        rs[ni] = rsqrtf(P[n0 + wc * 64 + ni * 16 + rl]);

    SBAR;

    float* Es = reinterpret_cast<float*>(Sm) + wave * 1088;
    #pragma unroll
    for (int mi = 0; mi < 4; ++mi) {
        #pragma unroll
        for (int ni = 0; ni < 4; ++ni)
            #pragma unroll
            for (int i = 0; i < 4; ++i)
                Es[((lane >> 4) * 4 + i) * 68 + ni * 16 + rl] = acc[mi][ni][i] * rs[ni];
        #pragma unroll
        for (int it = 0; it < 4; ++it) {
            const int f   = it * 64 + lane;
            const int row = f >> 4;
            const int c4  = f & 15;
            const float4 v = *reinterpret_cast<const float4*>(&Es[row * 68 + c4 * 4]);
            const int m = m0 + wr * 64 + mi * 16 + row;
            *reinterpret_cast<float4*>(&out[(size_t)m * M_TOT + n0 + wc * 64 + c4 * 4]) = v;
        }
    }
}

// ---------------- final fallback (round-1) ----------------

__global__ __launch_bounds__(256) void corr_gemm(const float* __restrict__ A,
                                                 const float* __restrict__ Bm,
                                                 float* __restrict__ out,
                                                 float* __restrict__ penalty)
{
    __shared__ short As[BM * BK];
    __shared__ short Bs[BN * BK];

    const int tid  = threadIdx.x;
    const int lane = tid & 63;
    const int wave = tid >> 6;
    const int wr   = wave >> 1;
    const int wc   = wave & 1;
    const int m0   = blockIdx.y * BM;
    const int n0   = blockIdx.x * BN;
    const int g_rd = lane >> 4;
    const int rl   = lane & 15;

    f32x4 acc[4][4] = {};

    for (int k0 = 0; k0 < C_TOT; k0 += BK) {
        #pragma unroll
        for (int half = 0; half < 2; ++half) {
            const int cc = tid + half * 256;
            const int r  = cc >> 2;
            const int g  = cc & 3;
            const int sg = g ^ ((r >> 1) & 3);

            const float4* pa = reinterpret_cast<const float4*>(
                A + (size_t)(m0 + r) * C_TOT + k0 + g * 8);
            float4 a0 = pa[0], a1 = pa[1];
            bf16x8 wa;
            wa[0]=f2bf(a0.x); wa[1]=f2bf(a0.y); wa[2]=f2bf(a0.z); wa[3]=f2bf(a0.w);
            wa[4]=f2bf(a1.x); wa[5]=f2bf(a1.y); wa[6]=f2bf(a1.z); wa[7]=f2bf(a1.w);
            *reinterpret_cast<bf16x8*>(&As[r * BK + sg * 8]) = wa;

            const float4* pb = reinterpret_cast<const float4*>(
                Bm + (size_t)(n0 + r) * C_TOT + k0 + g * 8);
            float4 b0 = pb[0], b1 = pb[1];
            bf16x8 wb;
            wb[0]=f2bf(b0.x); wb[1]=f2bf(b0.y); wb[2]=f2bf(b0.z); wb[3]=f2bf(b0.w);
            wb[4]=f2bf(b1.x); wb[5]=f2bf(b1.y); wb[6]=f2bf(b1.z); wb[7]=f2bf(b1.w);
            *reinterpret_cast<bf16x8*>(&Bs[r * BK + sg * 8]) = wb;
        }
        __syncthreads();

        bf16x8 af[4], bfr[4];
        #pragma unroll
        for (int mi = 0; mi < 4; ++mi) {
            const int r  = wr * 64 + mi * 16 + rl;
            const int sg = g_rd ^ ((r >> 1) & 3);
            af[mi] = *reinterpret_cast<const bf16x8*>(&As[r * BK + sg * 8]);
        }
        #pragma unroll
        for (int ni = 0; ni < 4; ++ni) {
            const int r  = wc * 64 + ni * 16 + rl;
            const int sg = g_rd ^ ((r >> 1) & 3);
            bfr[ni] = *reinterpret_cast<const bf16x8*>(&Bs[r * BK + sg * 8]);
        }
        #pragma unroll
        for (int mi = 0; mi < 4; ++mi)
            #pragma unroll
            for (int ni = 0; ni < 4; ++ni)
                acc[mi][ni] = __builtin_amdgcn_mfma_f32_16x16x32_bf16(
                    af[mi], bfr[ni], acc[mi][ni], 0, 0, 0);
        __syncthreads();
    }

    const float inv_c = 1.0f / (float)C_TOT;
    #pragma unroll
    for (int mi = 0; mi < 4; ++mi) {
        #pragma unroll
        for (int i = 0; i < 4; ++i) {
            const int m = m0 + wr * 64 + mi * 16 + (lane >> 4) * 4 + i;
            float s = 0.0f;
            #pragma unroll
            for (int ni = 0; ni < 4; ++ni) {
                const float v = acc[mi][ni][i] * inv_c;
                out[(size_t)m * M_TOT + n0 + wc * 64 + ni * 16 + rl] = v;
                s += v * v;
            }
            s += __shfl_xor(s, 1);
            s += __shfl_xor(s, 2);
            s += __shfl_xor(s, 4);
            s += __shfl_xor(s, 8);
            if (rl == 0) atomicAdd(&penalty[m], s);
        }
    }
}

__global__ __launch_bounds__(256) void scale_k(float* __restrict__ out,
                                               const float* __restrict__ penalty)
{
    const unsigned cols4 = M_TOT / 4;
    const unsigned total = (unsigned)M_TOT * cols4;
    float4* o4 = reinterpret_cast<float4*>(out);
    const float4* p4 = reinterpret_cast<const float4*>(penalty);
    for (unsigned idx = blockIdx.x * blockDim.x + threadIdx.x; idx < total;
         idx += gridDim.x * blockDim.x) {
        const unsigned n4 = idx % cols4;
        const float4 p = p4[n4];
        float4 v = o4[idx];
        v.x *= rsqrtf(p.x);
        v.y *= rsqrtf(p.y);
        v.z *= rsqrtf(p.z);
        v.w *= rsqrtf(p.w);
        o4[idx] = v;
    }
}

// ---------------- launch ----------------

extern "C" void kernel_launch(void* const* d_in, const int* in_sizes, int n_in,
                              void* d_out, int out_size, void* d_ws, size_t ws_size,
                              hipStream_t stream) {
    const float* A = (const float*)d_in[0];
    const float* B = (const float*)d_in[1];
    float* out     = (float*)d_out;

    const size_t mat_sh = (size_t)M_TOT * C_TOT;
    const size_t sz_ab  = mat_sh * sizeof(short);
    const size_t sz_gb  = (size_t)C_TOT * C_TOT * sizeof(short);
    const size_t sz_p   = (size_t)M_TOT * sizeof(float);
    const size_t sz_gq  = (size_t)C_TOT * C_TOT * sizeof(float);
    const size_t base_need = 3 * sz_ab + sz_gb + sz_p;
    const size_t need_f40  = base_need + 40 * sz_gq;           // ~20.5 MB
    const size_t need_f20  = base_need + 20 * sz_gq;           // ~15.3 MB
    const size_t need_mid  = 2 * sz_ab + sz_p;                 // ~6.6 MB

    dim3 grid2(NTILE, NTILE);

    if (ws_size >= need_f20) {
        short* Ab = (short*)d_ws;
        short* Bb = Ab + mat_sh;
        short* Bt = Bb + mat_sh;
        short* Gb = Bt + mat_sh;
        float* P  = (float*)((char*)d_ws + 3 * sz_ab + sz_gb);
        float* Gp = (float*)((char*)d_ws + 3 * sz_ab + sz_gb + sz_p);

        prep<<<500, 256, 0, stream>>>(A, B, Ab, Bb, Bt, P);
        if (ws_size >= need_f40) {
            gemm_G<5><<<dim3(2, 2, 40), 512, 0, stream>>>(Bt, Gp);
            g_reduce<<<64, 256, 0, stream>>>(Gp, Gb, 40);
        } else {
            gemm_G<10><<<dim3(2, 2, 20), 512, 0, stream>>>(Bt, Gp);
            g_reduce<<<64, 256, 0, stream>>>(Gp, Gb, 20);
        }
        penalty_q<<<dim3(NTILE, 4), 512, 0, stream>>>(Ab, Gb, P);
        gemm_out<<<NTILE * NTILE, 512, 0, stream>>>(Ab, Bb, P, out);
    } else if (ws_size >= need_mid) {
        short* Ab = (short*)d_ws;
        short* Bb = Ab + mat_sh;
        float* P  = (float*)(Bb + mat_sh);

        (void)hipMemsetAsync(P, 0, sz_p, stream);
        convert_ab<<<1600, 256, 0, stream>>>(A, B, Ab, Bb);
        gemm_penalty<<<grid2, dim3(256), 0, stream>>>(Ab, Bb, P);
        gemm_out_plain<<<grid2, dim3(256), 0, stream>>>(Ab, Bb, P, out);
    } else {
        float* penalty = (float*)d_ws;
        (void)hipMemsetAsync(penalty, 0, sz_p, stream);
        corr_gemm<<<grid2, dim3(256), 0, stream>>>(A, B, out, penalty);
        scale_k<<<2048, 256, 0, stream>>>(out, penalty);
    }
}

// Round 17
// 78.523 us; speedup vs baseline: 1.0270x; 1.0270x over previous
//
#include <hip/hip_runtime.h>

typedef __attribute__((ext_vector_type(8))) short bf16x8;
typedef __attribute__((ext_vector_type(4))) float f32x4;

#define M_TOT 6400   // 80*80 flattened spatial positions
#define C_TOT 256    // channels (K of the main GEMM)
#define BM 128
#define BN 128
#define BK 32
#define NTILE 50     // 6400 / 128

#define VMCNT0 asm volatile("s_waitcnt vmcnt(0)" ::: "memory")
#define VMCNT2 asm volatile("s_waitcnt vmcnt(2)" ::: "memory")
#define VMCNT4 asm volatile("s_waitcnt vmcnt(4)" ::: "memory")
#define SBAR   __builtin_amdgcn_s_barrier()

// f32 -> bf16 round-to-nearest-even
__device__ __forceinline__ short f2bf(float f) {
    unsigned u = __float_as_uint(f);
    u = (u + 0x7fffu + ((u >> 16) & 1u)) >> 16;
    return (short)u;
}
__device__ __forceinline__ float bf2f(short s) {
    return __uint_as_float(((unsigned)(unsigned short)s) << 16);
}

// non-temporal 16B f32 load (read-once data: don't allocate in L2)
__device__ __forceinline__ f32x4 ntload4(const float* p) {
    return __builtin_nontemporal_load(reinterpret_cast<const f32x4*>(p));
}

// async global->LDS, 16B per lane; LDS dst is wave-uniform base + lane*16
__device__ __forceinline__ void gload16(const short* g, short* l) {
    __builtin_amdgcn_global_load_lds(
        (const __attribute__((address_space(1))) void*)g,
        (__attribute__((address_space(3))) void*)l, 16, 0, 0);
}

// ---------------- fused prep: A->Ab, B->(Bb,Bt), zero P ----------------
// f32 inputs are read exactly once -> nt loads keep the bf16 outputs
// (which the whole downstream chain re-reads) resident in L2.

__global__ __launch_bounds__(256) void prep(const float* __restrict__ A,
                                            const float* __restrict__ Bm,
                                            short* __restrict__ Ab,
                                            short* __restrict__ Bb,
                                            short* __restrict__ Bt,
                                            float* __restrict__ P)
{
    __shared__ __align__(16) short Lb[64][72];
    const int bid = blockIdx.x;
    const int t   = threadIdx.x;

    if (bid < 400) {
        const int n0 = (bid % 100) * 64;
        const int c0 = (bid / 100) * 64;
        const int r  = t >> 2;
        const int cb = (t & 3) * 16;

        const float* src = Bm + (size_t)(n0 + r) * C_TOT + c0 + cb;
        const f32x4 v0 = ntload4(src), v1 = ntload4(src + 4);
        const f32x4 v2 = ntload4(src + 8), v3 = ntload4(src + 12);
        bf16x8 w0, w1;
        w0[0]=f2bf(v0[0]); w0[1]=f2bf(v0[1]); w0[2]=f2bf(v0[2]); w0[3]=f2bf(v0[3]);
        w0[4]=f2bf(v1[0]); w0[5]=f2bf(v1[1]); w0[6]=f2bf(v1[2]); w0[7]=f2bf(v1[3]);
        w1[0]=f2bf(v2[0]); w1[1]=f2bf(v2[1]); w1[2]=f2bf(v2[2]); w1[3]=f2bf(v2[3]);
        w1[4]=f2bf(v3[0]); w1[5]=f2bf(v3[1]); w1[6]=f2bf(v3[2]); w1[7]=f2bf(v3[3]);
        *reinterpret_cast<bf16x8*>(&Lb[r][cb])     = w0;
        *reinterpret_cast<bf16x8*>(&Lb[r][cb + 8]) = w1;
        short* brow = Bb + (size_t)(n0 + r) * C_TOT + c0 + cb;
        *reinterpret_cast<bf16x8*>(brow)     = w0;
        *reinterpret_cast<bf16x8*>(brow + 8) = w1;
        __syncthreads();

        #pragma unroll
        for (int p = 0; p < 2; ++p) {
            const int q = t + p * 256;
            const int c = q >> 3;
            const int h = q & 7;
            bf16x8 w;
            #pragma unroll
            for (int j = 0; j < 8; ++j) w[j] = Lb[h * 8 + j][c];
            *reinterpret_cast<bf16x8*>(&Bt[(size_t)(c0 + c) * M_TOT + n0 + h * 8]) = w;
        }
    } else {
        const int aid = bid - 400;   // 0..99
        if (aid == 0)
            for (int j = t; j < M_TOT; j += 256) P[j] = 0.0f;
        const int base = aid * 2048;
        #pragma unroll
        for (int it = 0; it < 8; ++it) {
            const int i = base + it * 256 + t;
            const f32x4 v0 = ntload4(A + (size_t)i * 8);
            const f32x4 v1 = ntload4(A + (size_t)i * 8 + 4);
            bf16x8 w;
            w[0]=f2bf(v0[0]); w[1]=f2bf(v0[1]); w[2]=f2bf(v0[2]); w[3]=f2bf(v0[3]);
            w[4]=f2bf(v1[0]); w[5]=f2bf(v1[1]); w[6]=f2bf(v1[2]); w[7]=f2bf(v1[3]);
            *reinterpret_cast<bf16x8*>(Ab + (size_t)i * 8) = w;
        }
    }
}

// ------- 4-wave staged 128x128 tile machinery (fallback paths) -------

__device__ __forceinline__ void stage_tiles_g(const short* __restrict__ A,
                                              const short* __restrict__ B,
                                              int m0, int n0, int k0,
                                              int lda, int ldb,
                                              short* As, short* Bs,
                                              int wave, int lane)
{
    #pragma unroll
    for (int t = 0; t < 2; ++t) {
        const int c  = (wave * 2 + t) * 64 + lane;
        const int r  = c >> 2;
        const int g  = c & 3;
        const int sg = g ^ ((r >> 1) & 3);
        gload16(A + (size_t)(m0 + r) * lda + k0 + sg * 8, As + (wave * 2 + t) * 512);
        gload16(B + (size_t)(n0 + r) * ldb + k0 + sg * 8, Bs + (wave * 2 + t) * 512);
    }
}

template<int KSTEPS>
__device__ __forceinline__ void gemm_tile_g(const short* __restrict__ A,
                                            const short* __restrict__ B,
                                            int m0, int n0, int kbase,
                                            int lda, int ldb, int tid,
                                            short (*Sm)[2][4096],
                                            f32x4 acc[4][4])
{
    const int lane = tid & 63;
    const int wave = tid >> 6;
    const int rl   = lane & 15;
    const int g_rd = lane >> 4;
    const int wr   = wave >> 1;
    const int wc   = wave & 1;

    stage_tiles_g(A, B, m0, n0, kbase, lda, ldb, &Sm[0][0][0], &Sm[0][1][0], wave, lane);
    if (KSTEPS > 1)
        stage_tiles_g(A, B, m0, n0, kbase + BK, lda, ldb,
                      &Sm[1][0][0], &Sm[1][1][0], wave, lane);
    if (KSTEPS > 1) { VMCNT4; } else { VMCNT0; }
    SBAR;

    #pragma unroll
    for (int kt = 0; kt < KSTEPS; ++kt) {
        const int cur = kt % 3;
        if (kt + 2 < KSTEPS)
            stage_tiles_g(A, B, m0, n0, kbase + (kt + 2) * BK, lda, ldb,
                          &Sm[(kt + 2) % 3][0][0], &Sm[(kt + 2) % 3][1][0], wave, lane);

        bf16x8 af[4], bfr[4];
        #pragma unroll
        for (int mi = 0; mi < 4; ++mi) {
            const int r  = wr * 64 + mi * 16 + rl;
            const int sg = g_rd ^ ((r >> 1) & 3);
            af[mi] = *reinterpret_cast<const bf16x8*>(&Sm[cur][0][r * BK + sg * 8]);
        }
        #pragma unroll
        for (int ni = 0; ni < 4; ++ni) {
            const int r  = wc * 64 + ni * 16 + rl;
            const int sg = g_rd ^ ((r >> 1) & 3);
            bfr[ni] = *reinterpret_cast<const bf16x8*>(&Sm[cur][1][r * BK + sg * 8]);
        }
        __builtin_amdgcn_s_setprio(1);
        #pragma unroll
        for (int mi = 0; mi < 4; ++mi)
            #pragma unroll
            for (int ni = 0; ni < 4; ++ni)
                acc[mi][ni] = __builtin_amdgcn_mfma_f32_16x16x32_bf16(
                    af[mi], bfr[ni], acc[mi][ni], 0, 0, 0);
        __builtin_amdgcn_s_setprio(0);

        if (kt + 1 < KSTEPS) {
            if (kt + 2 < KSTEPS) { VMCNT4; } else { VMCNT0; }
            SBAR;
        }
    }
}

// ------- 8-wave (512-thread) staged 128x128 tile: per-wave 64x32, acc[4][2] -------
// Stage = 2 gload16/thread; counted wait vmcnt(2); LDS 16 KB/buf x 3 = 48 KB.

__device__ __forceinline__ void stage_g512(const short* __restrict__ A,
                                           const short* __restrict__ B,
                                           int m0, int n0, int k0,
                                           int lda, int ldb,
                                           short* buf, int wave, int lane)
{
    const int c  = wave * 64 + lane;   // 0..511
    const int r  = c >> 2;              // 0..127
    const int g  = c & 3;
    const int sg = g ^ ((r >> 1) & 3);
    gload16(A + (size_t)(m0 + r) * lda + k0 + sg * 8, buf + wave * 512);
    gload16(B + (size_t)(n0 + r) * ldb + k0 + sg * 8, buf + 4096 + wave * 512);
}

template<int KSTEPS>
__device__ __forceinline__ void gemm_tile_512g(const short* __restrict__ A,
                                               const short* __restrict__ B,
                                               int m0, int n0, int kbase,
                                               int lda, int ldb, int tid,
                                               short (*Sm)[8192],
                                               f32x4 acc[4][2])
{
    const int lane = tid & 63;
    const int wave = tid >> 6;        // 0..7
    const int rl   = lane & 15;
    const int g_rd = lane >> 4;
    const int wr   = wave >> 2;       // 0..1
    const int wc   = wave & 3;        // 0..3

    stage_g512(A, B, m0, n0, kbase, lda, ldb, Sm[0], wave, lane);
    if (KSTEPS > 1)
        stage_g512(A, B, m0, n0, kbase + BK, lda, ldb, Sm[1], wave, lane);
    if (KSTEPS > 1) { VMCNT2; } else { VMCNT0; }
    SBAR;

    #pragma unroll
    for (int kt = 0; kt < KSTEPS; ++kt) {
        const int cur = kt % 3;
        if (kt + 2 < KSTEPS)
            stage_g512(A, B, m0, n0, kbase + (kt + 2) * BK, lda, ldb,
                       Sm[(kt + 2) % 3], wave, lane);

        bf16x8 af[4], bfr[2];
        #pragma unroll
        for (int mi = 0; mi < 4; ++mi) {
            const int rr = wr * 64 + mi * 16 + rl;
            const int sg = g_rd ^ ((rr >> 1) & 3);
            af[mi] = *reinterpret_cast<const bf16x8*>(&Sm[cur][rr * BK + sg * 8]);
        }
        #pragma unroll
        for (int ni = 0; ni < 2; ++ni) {
            const int rr = wc * 32 + ni * 16 + rl;
            const int sg = g_rd ^ ((rr >> 1) & 3);
            bfr[ni] = *reinterpret_cast<const bf16x8*>(&Sm[cur][4096 + rr * BK + sg * 8]);
        }
        __builtin_amdgcn_s_setprio(1);
        #pragma unroll
        for (int mi = 0; mi < 4; ++mi)
            #pragma unroll
            for (int ni = 0; ni < 2; ++ni)
                acc[mi][ni] = __builtin_amdgcn_mfma_f32_16x16x32_bf16(
                    af[mi], bfr[ni], acc[mi][ni], 0, 0, 0);
        __builtin_amdgcn_s_setprio(0);

        if (kt + 1 < KSTEPS) {
            if (kt + 2 < KSTEPS) { VMCNT2; } else { VMCNT0; }
            SBAR;
        }
    }
}

// ---------------- Gram path (512-thread / 8-wave) ----------------

template<int STEPS>
__global__ __launch_bounds__(512, 4) void gemm_G(const short* __restrict__ Bt,
                                                 float* __restrict__ Gp)
{
    __shared__ __align__(16) short Sm[3][8192];   // 48 KB
    const int tid = threadIdx.x;
    const int m0 = blockIdx.y * BM, n0 = blockIdx.x * BN;
    const int z  = blockIdx.z;
    f32x4 acc[4][2] = {};
    gemm_tile_512g<STEPS>(Bt, Bt, m0, n0, z * (STEPS * BK),
                          M_TOT, M_TOT, tid, Sm, acc);

    float* dst = Gp + (size_t)z * (C_TOT * C_TOT);
    const int lane = tid & 63, rl = lane & 15;
    const int wave = tid >> 6, wr = wave >> 2, wc = wave & 3;
    #pragma unroll
    for (int mi = 0; mi < 4; ++mi)
        #pragma unroll
        for (int i = 0; i < 4; ++i) {
            const int m = m0 + wr * 64 + mi * 16 + (lane >> 4) * 4 + i;
            #pragma unroll
            for (int ni = 0; ni < 2; ++ni)
                dst[m * C_TOT + n0 + wc * 32 + ni * 16 + rl] = acc[mi][ni][i];
        }
}

__global__ __launch_bounds__(256) void g_reduce(const float* __restrict__ Gp,
                                                short* __restrict__ Gb,
                                                int nchunks)
{
    const int i4 = blockIdx.x * 256 + threadIdx.x;
    float4 s = make_float4(0.f, 0.f, 0.f, 0.f);
    for (int z = 0; z < nchunks; ++z) {
        const float4 v = reinterpret_cast<const float4*>(
            Gp + (size_t)z * (C_TOT * C_TOT))[i4];
        s.x += v.x; s.y += v.y; s.z += v.z; s.w += v.w;
    }
    short4 o;
    o.x = f2bf(s.x); o.y = f2bf(s.y); o.z = f2bf(s.z); o.w = f2bf(s.w);
    reinterpret_cast<short4*>(Gb)[i4] = o;
}

// P[m] += sum over quadrant (ci, cj); 512-thread / 8-wave
__global__ __launch_bounds__(512, 4) void penalty_q(const short* __restrict__ Ab,
                                                    const short* __restrict__ Gb,
                                                    float* __restrict__ P)
{
    __shared__ __align__(16) short Sm[3][8192];
    const int tid = threadIdx.x;
    const int m0 = blockIdx.x * BM;
    const int ci = blockIdx.y & 1, cj = blockIdx.y >> 1;
    const int lane = tid & 63, rl = lane & 15;
    const int wave = tid >> 6, wr = wave >> 2, wc = wave & 3;

    f32x4 acc[4][2] = {};
    gemm_tile_512g<4>(Ab, Gb + (size_t)(cj * BM) * C_TOT, m0, 0, ci * BM,
                      C_TOT, C_TOT, tid, Sm, acc);

    #pragma unroll
    for (int mi = 0; mi < 4; ++mi)
        #pragma unroll
        for (int i = 0; i < 4; ++i) {
            const int m = m0 + wr * 64 + mi * 16 + (lane >> 4) * 4 + i;
            float s = 0.0f;
            #pragma unroll
            for (int ni = 0; ni < 2; ++ni) {
                const int cp = cj * BM + wc * 32 + ni * 16 + rl;
                s += acc[mi][ni][i] * bf2f(Ab[(size_t)m * C_TOT + cp]);
            }
            s += __shfl_xor(s, 1);
            s += __shfl_xor(s, 2);
            s += __shfl_xor(s, 4);
            s += __shfl_xor(s, 8);
            if (rl == 0) atomicAdd(&P[m], s);
        }
}

// ------- output GEMM: 128x128 tile, 512 threads / 8 waves, 3 blocks/CU -------
// (round-15 config: best measured, 6 waves/SIMD + 3-buffer counted-vmcnt)

__global__ __launch_bounds__(512, 6) void gemm_out(const short* __restrict__ Ab,
                                                   const short* __restrict__ Bb,
                                                   const float* __restrict__ P,
                                                   float* __restrict__ out)
{
    __shared__ __align__(16) short Sm[3][8192];   // 48 KB
    const int tid = threadIdx.x;
    const int lane = tid & 63, rl = lane & 15;
    const int wave = tid >> 6;            // 0..7
    const int wr   = wave >> 2;           // 0..1  (m half)
    const int wc   = wave & 3;            // 0..3  (n quarter)

    // bijective chunked XCD swizzle (m204): 2500 blocks, 8 XCDs (q=312, r=4)
    const int nwg = NTILE * NTILE, q = nwg >> 3, r = nwg & 7;
    const int orig = blockIdx.x;
    const int xcd = orig & 7, idx = orig >> 3;
    const int wg = (xcd < r ? xcd * (q + 1) : r * (q + 1) + (xcd - r) * q) + idx;
    const int m0 = (wg / NTILE) * BM;
    const int n0 = (wg % NTILE) * BN;

    f32x4 acc[4][2] = {};
    gemm_tile_512g<8>(Ab, Bb, m0, n0, 0, C_TOT, C_TOT, tid, Sm, acc);

    float rs[2];
    #pragma unroll
    for (int ni = 0; ni < 2; ++ni)
        rs[ni] = rsqrtf(P[n0 + wc * 32 + ni * 16 + rl]);

    SBAR;   // all waves done reading Sm before epilogue scratch reuse

    // wave-private 16x36 f32 scratch (8 waves x 2304 B = 18 KB, aliased on Sm)
    float* Es = reinterpret_cast<float*>(Sm) + wave * 576;
    #pragma unroll
    for (int mi = 0; mi < 4; ++mi) {
        #pragma unroll
        for (int ni = 0; ni < 2; ++ni)
            #pragma unroll
            for (int i = 0; i < 4; ++i)
                Es[((lane >> 4) * 4 + i) * 36 + ni * 16 + rl] = acc[mi][ni][i] * rs[ni];
        #pragma unroll
        for (int it = 0; it < 2; ++it) {
            const int f   = it * 64 + lane;   // 0..127
            const int row = f >> 3;           // 0..15
            const int c4  = f & 7;            // float4 column 0..7
            const f32x4 v = *reinterpret_cast<const f32x4*>(&Es[row * 36 + c4 * 4]);
            const int m = m0 + wr * 64 + mi * 16 + row;
            __builtin_nontemporal_store(v, reinterpret_cast<f32x4*>(
                &out[(size_t)m * M_TOT + n0 + wc * 32 + c4 * 4]));
        }
    }
}

// ---------------- mid fallback: two-GEMM (128^2, staged, 4-wave) ----------------

__global__ __launch_bounds__(256) void convert_ab(const float* __restrict__ A,
                                                  const float* __restrict__ Bm,
                                                  short* __restrict__ Ab,
                                                  short* __restrict__ Bb)
{
    const int n8 = M_TOT * C_TOT / 8;
    for (int i = blockIdx.x * blockDim.x + threadIdx.x; i < 2 * n8;
         i += gridDim.x * blockDim.x) {
        const float* s = (i < n8) ? (A + (size_t)i * 8) : (Bm + (size_t)(i - n8) * 8);
        short* d       = (i < n8) ? (Ab + (size_t)i * 8) : (Bb + (size_t)(i - n8) * 8);
        const float4 v0 = reinterpret_cast<const float4*>(s)[0];
        const float4 v1 = reinterpret_cast<const float4*>(s)[1];
        bf16x8 w;
        w[0]=f2bf(v0.x); w[1]=f2bf(v0.y); w[2]=f2bf(v0.z); w[3]=f2bf(v0.w);
        w[4]=f2bf(v1.x); w[5]=f2bf(v1.y); w[6]=f2bf(v1.z); w[7]=f2bf(v1.w);
        *reinterpret_cast<bf16x8*>(d) = w;
    }
}

__global__ __launch_bounds__(256) void gemm_penalty(const short* __restrict__ Ab,
                                                    const short* __restrict__ Bb,
                                                    float* __restrict__ P)
{
    __shared__ __align__(16) short Sm[3][2][4096];
    const int tid = threadIdx.x;
    const int m0 = blockIdx.y * BM, n0 = blockIdx.x * BN;
    f32x4 acc[4][4] = {};
    gemm_tile_g<8>(Ab, Bb, m0, n0, 0, C_TOT, C_TOT, tid, Sm, acc);

    const int lane = tid & 63, rl = lane & 15;
    const int wave = tid >> 6, wr = wave >> 1;
    #pragma unroll
    for (int mi = 0; mi < 4; ++mi) {
        #pragma unroll
        for (int i = 0; i < 4; ++i) {
            const int m = m0 + wr * 64 + mi * 16 + (lane >> 4) * 4 + i;
            float s = 0.0f;
            #pragma unroll
            for (int ni = 0; ni < 4; ++ni) {
                const float v = acc[mi][ni][i];
                s += v * v;
            }
            s += __shfl_xor(s, 1);
            s += __shfl_xor(s, 2);
            s += __shfl_xor(s, 4);
            s += __shfl_xor(s, 8);
            if (rl == 0) atomicAdd(&P[m], s);
        }
    }
}

__global__ __launch_bounds__(256) void gemm_out_plain(const short* __restrict__ Ab,
                                                      const short* __restrict__ Bb,
                                                      const float* __restrict__ P,
                                                      float* __restrict__ out)
{
    __shared__ __align__(16) short Sm[3][2][4096];
    const int tid = threadIdx.x;
    const int lane = tid & 63, rl = lane & 15;
    const int wave = tid >> 6, wr = wave >> 1, wc = wave & 1;
    const int m0 = blockIdx.y * BM, n0 = blockIdx.x * BN;

    f32x4 acc[4][4] = {};
    gemm_tile_g<8>(Ab, Bb, m0, n0, 0, C_TOT, C_TOT, tid, Sm, acc);

    float rs[4];
    #pragma unroll
    for (int ni = 0; ni < 4; ++ni)
        rs[ni] = rsqrtf(P[n0 + wc * 64 + ni * 16 + rl]);

    SBAR;

    float* Es = reinterpret_cast<float*>(Sm) + wave * 1088;
    #pragma unroll
    for (int mi = 0; mi < 4; ++mi) {
        #pragma unroll
        for (int ni = 0; ni < 4; ++ni)
            #pragma unroll
            for (int i = 0; i < 4; ++i)
                Es[((lane >> 4) * 4 + i) * 68 + ni * 16 + rl] = acc[mi][ni][i] * rs[ni];
        #pragma unroll
        for (int it = 0; it < 4; ++it) {
            const int f   = it * 64 + lane;
            const int row = f >> 4;
            const int c4  = f & 15;
            const float4 v = *reinterpret_cast<const float4*>(&Es[row * 68 + c4 * 4]);
            const int m = m0 + wr * 64 + mi * 16 + row;
            *reinterpret_cast<float4*>(&out[(size_t)m * M_TOT + n0 + wc * 64 + c4 * 4]) = v;
        }
    }
}

// ---------------- final fallback (round-1) ----------------

__global__ __launch_bounds__(256) void corr_gemm(const float* __restrict__ A,
                                                 const float* __restrict__ Bm,
                                                 float* __restrict__ out,
                                                 float* __restrict__ penalty)
{
    __shared__ short As[BM * BK];
    __shared__ short Bs[BN * BK];

    const int tid  = threadIdx.x;
    const int lane = tid & 63;
    const int wave = tid >> 6;
    const int wr   = wave >> 1;
    const int wc   = wave & 1;
    const int m0   = blockIdx.y * BM;
    const int n0   = blockIdx.x * BN;
    const int g_rd = lane >> 4;
    const int rl   = lane & 15;

    f32x4 acc[4][4] = {};

    for (int k0 = 0; k0 < C_TOT; k0 += BK) {
        #pragma unroll
        for (int half = 0; half < 2; ++half) {
            const int cc = tid + half * 256;
            const int r  = cc >> 2;
            const int g  = cc & 3;
            const int sg = g ^ ((r >> 1) & 3);

            const float4* pa = reinterpret_cast<const float4*>(
                A + (size_t)(m0 + r) * C_TOT + k0 + g * 8);
            float4 a0 = pa[0], a1 = pa[1];
            bf16x8 wa;
            wa[0]=f2bf(a0.x); wa[1]=f2bf(a0.y); wa[2]=f2bf(a0.z); wa[3]=f2bf(a0.w);
            wa[4]=f2bf(a1.x); wa[5]=f2bf(a1.y); wa[6]=f2bf(a1.z); wa[7]=f2bf(a1.w);
            *reinterpret_cast<bf16x8*>(&As[r * BK + sg * 8]) = wa;

            const float4* pb = reinterpret_cast<const float4*>(
                Bm + (size_t)(n0 + r) * C_TOT + k0 + g * 8);
            float4 b0 = pb[0], b1 = pb[1];
            bf16x8 wb;
            wb[0]=f2bf(b0.x); wb[1]=f2bf(b0.y); wb[2]=f2bf(b0.z); wb[3]=f2bf(b0.w);
            wb[4]=f2bf(b1.x); wb[5]=f2bf(b1.y); wb[6]=f2bf(b1.z); wb[7]=f2bf(b1.w);
            *reinterpret_cast<bf16x8*>(&Bs[r * BK + sg * 8]) = wb;
        }
        __syncthreads();

        bf16x8 af[4], bfr[4];
        #pragma unroll
        for (int mi = 0; mi < 4; ++mi) {
            const int r  = wr * 64 + mi * 16 + rl;
            const int sg = g_rd ^ ((r >> 1) & 3);
            af[mi] = *reinterpret_cast<const bf16x8*>(&As[r * BK + sg * 8]);
        }
        #pragma unroll
        for (int ni = 0; ni < 4; ++ni) {
            const int r  = wc * 64 + ni * 16 + rl;
            const int sg = g_rd ^ ((r >> 1) & 3);
            bfr[ni] = *reinterpret_cast<const bf16x8*>(&Bs[r * BK + sg * 8]);
        }
        #pragma unroll
        for (int mi = 0; mi < 4; ++mi)
            #pragma unroll
            for (int ni = 0; ni < 4; ++ni)
                acc[mi][ni] = __builtin_amdgcn_mfma_f32_16x16x32_bf16(
                    af[mi], bfr[ni], acc[mi][ni], 0, 0, 0);
        __syncthreads();
    }

    const float inv_c = 1.0f / (float)C_TOT;
    #pragma unroll
    for (int mi = 0; mi < 4; ++mi) {
        #pragma unroll
        for (int i = 0; i < 4; ++i) {
            const int m = m0 + wr * 64 + mi * 16 + (lane >> 4) * 4 + i;
            float s = 0.0f;
            #pragma unroll
            for (int ni = 0; ni < 4; ++ni) {
                const float v = acc[mi][ni][i] * inv_c;
                out[(size_t)m * M_TOT + n0 + wc * 64 + ni * 16 + rl] = v;
                s += v * v;
            }
            s += __shfl_xor(s, 1);
            s += __shfl_xor(s, 2);
            s += __shfl_xor(s, 4);
            s += __shfl_xor(s, 8);
            if (rl == 0) atomicAdd(&penalty[m], s);
        }
    }
}

__global__ __launch_bounds__(256) void scale_k(float* __restrict__ out,
                                               const float* __restrict__ penalty)
{
    const unsigned cols4 = M_TOT / 4;
    const unsigned total = (unsigned)M_TOT * cols4;
    float4* o4 = reinterpret_cast<float4*>(out);
    const float4* p4 = reinterpret_cast<const float4*>(penalty);
    for (unsigned idx = blockIdx.x * blockDim.x + threadIdx.x; idx < total;
         idx += gridDim.x * blockDim.x) {
        const unsigned n4 = idx % cols4;
        const float4 p = p4[n4];
        float4 v = o4[idx];
        v.x *= rsqrtf(p.x);
        v.y *= rsqrtf(p.y);
        v.z *= rsqrtf(p.z);
        v.w *= rsqrtf(p.w);
        o4[idx] = v;
    }
}

// ---------------- launch ----------------

extern "C" void kernel_launch(void* const* d_in, const int* in_sizes, int n_in,
                              void* d_out, int out_size, void* d_ws, size_t ws_size,
                              hipStream_t stream) {
    const float* A = (const float*)d_in[0];
    const float* B = (const float*)d_in[1];
    float* out     = (float*)d_out;

    const size_t mat_sh = (size_t)M_TOT * C_TOT;
    const size_t sz_ab  = mat_sh * sizeof(short);
    const size_t sz_gb  = (size_t)C_TOT * C_TOT * sizeof(short);
    const size_t sz_p   = (size_t)M_TOT * sizeof(float);
    const size_t sz_gq  = (size_t)C_TOT * C_TOT * sizeof(float);
    const size_t base_need = 3 * sz_ab + sz_gb + sz_p;
    const size_t need_f40  = base_need + 40 * sz_gq;           // ~20.5 MB
    const size_t need_f20  = base_need + 20 * sz_gq;           // ~15.3 MB
    const size_t need_mid  = 2 * sz_ab + sz_p;                 // ~6.6 MB

    dim3 grid2(NTILE, NTILE);

    if (ws_size >= need_f20) {
        short* Ab = (short*)d_ws;
        short* Bb = Ab + mat_sh;
        short* Bt = Bb + mat_sh;
        short* Gb = Bt + mat_sh;
        float* P  = (float*)((char*)d_ws + 3 * sz_ab + sz_gb);
        float* Gp = (float*)((char*)d_ws + 3 * sz_ab + sz_gb + sz_p);

        prep<<<500, 256, 0, stream>>>(A, B, Ab, Bb, Bt, P);
        if (ws_size >= need_f40) {
            gemm_G<5><<<dim3(2, 2, 40), 512, 0, stream>>>(Bt, Gp);
            g_reduce<<<64, 256, 0, stream>>>(Gp, Gb, 40);
        } else {
            gemm_G<10><<<dim3(2, 2, 20), 512, 0, stream>>>(Bt, Gp);
            g_reduce<<<64, 256, 0, stream>>>(Gp, Gb, 20);
        }
        penalty_q<<<dim3(NTILE, 4), 512, 0, stream>>>(Ab, Gb, P);
        gemm_out<<<NTILE * NTILE, 512, 0, stream>>>(Ab, Bb, P, out);
    } else if (ws_size >= need_mid) {
        short* Ab = (short*)d_ws;
        short* Bb = Ab + mat_sh;
        float* P  = (float*)(Bb + mat_sh);

        (void)hipMemsetAsync(P, 0, sz_p, stream);
        convert_ab<<<1600, 256, 0, stream>>>(A, B, Ab, Bb);
        gemm_penalty<<<grid2, dim3(256), 0, stream>>>(Ab, Bb, P);
        gemm_out_plain<<<grid2, dim3(256), 0, stream>>>(Ab, Bb, P, out);
    } else {
        float* penalty = (float*)d_ws;
        (void)hipMemsetAsync(penalty, 0, sz_p, stream);
        corr_gemm<<<grid2, dim3(256), 0, stream>>>(A, B, out, penalty);
        scale_k<<<2048, 256, 0, stream>>>(out, penalty);
    }
}

// Round 18
// 75.411 us; speedup vs baseline: 1.0694x; 1.0413x over previous
//
#include <hip/hip_runtime.h>

typedef __attribute__((ext_vector_type(8))) short bf16x8;
typedef __attribute__((ext_vector_type(4))) float f32x4;

#define M_TOT 6400   // 80*80 flattened spatial positions
#define C_TOT 256    // channels (K of the main GEMM)
#define BM 128
#define BN 128
#define BK 32
#define NTILE 50     // 6400 / 128

#define VMCNT0 asm volatile("s_waitcnt vmcnt(0)" ::: "memory")
#define VMCNT2 asm volatile("s_waitcnt vmcnt(2)" ::: "memory")
#define VMCNT4 asm volatile("s_waitcnt vmcnt(4)" ::: "memory")
#define SBAR   __builtin_amdgcn_s_barrier()

// f32 -> bf16 round-to-nearest-even
__device__ __forceinline__ short f2bf(float f) {
    unsigned u = __float_as_uint(f);
    u = (u + 0x7fffu + ((u >> 16) & 1u)) >> 16;
    return (short)u;
}
__device__ __forceinline__ float bf2f(short s) {
    return __uint_as_float(((unsigned)(unsigned short)s) << 16);
}

// async global->LDS, 16B per lane; LDS dst is wave-uniform base + lane*16
__device__ __forceinline__ void gload16(const short* g, short* l) {
    __builtin_amdgcn_global_load_lds(
        (const __attribute__((address_space(1))) void*)g,
        (__attribute__((address_space(3))) void*)l, 16, 0, 0);
}

// ---------------- fused prep: A->Ab, B->(Bb,Bt), zero P ----------------

__global__ __launch_bounds__(256) void prep(const float* __restrict__ A,
                                            const float* __restrict__ Bm,
                                            short* __restrict__ Ab,
                                            short* __restrict__ Bb,
                                            short* __restrict__ Bt,
                                            float* __restrict__ P)
{
    __shared__ __align__(16) short Lb[64][72];
    const int bid = blockIdx.x;
    const int t   = threadIdx.x;

    if (bid < 400) {
        const int n0 = (bid % 100) * 64;
        const int c0 = (bid / 100) * 64;
        const int r  = t >> 2;
        const int cb = (t & 3) * 16;

        const float4* src = reinterpret_cast<const float4*>(
            Bm + (size_t)(n0 + r) * C_TOT + c0 + cb);
        const float4 v0 = src[0], v1 = src[1], v2 = src[2], v3 = src[3];
        bf16x8 w0, w1;
        w0[0]=f2bf(v0.x); w0[1]=f2bf(v0.y); w0[2]=f2bf(v0.z); w0[3]=f2bf(v0.w);
        w0[4]=f2bf(v1.x); w0[5]=f2bf(v1.y); w0[6]=f2bf(v1.z); w0[7]=f2bf(v1.w);
        w1[0]=f2bf(v2.x); w1[1]=f2bf(v2.y); w1[2]=f2bf(v2.z); w1[3]=f2bf(v2.w);
        w1[4]=f2bf(v3.x); w1[5]=f2bf(v3.y); w1[6]=f2bf(v3.z); w1[7]=f2bf(v3.w);
        *reinterpret_cast<bf16x8*>(&Lb[r][cb])     = w0;
        *reinterpret_cast<bf16x8*>(&Lb[r][cb + 8]) = w1;
        short* brow = Bb + (size_t)(n0 + r) * C_TOT + c0 + cb;
        *reinterpret_cast<bf16x8*>(brow)     = w0;
        *reinterpret_cast<bf16x8*>(brow + 8) = w1;
        __syncthreads();

        #pragma unroll
        for (int p = 0; p < 2; ++p) {
            const int q = t + p * 256;
            const int c = q >> 3;
            const int h = q & 7;
            bf16x8 w;
            #pragma unroll
            for (int j = 0; j < 8; ++j) w[j] = Lb[h * 8 + j][c];
            *reinterpret_cast<bf16x8*>(&Bt[(size_t)(c0 + c) * M_TOT + n0 + h * 8]) = w;
        }
    } else {
        const int aid = bid - 400;   // 0..99
        if (aid == 0)
            for (int j = t; j < M_TOT; j += 256) P[j] = 0.0f;
        const int base = aid * 2048;
        #pragma unroll
        for (int it = 0; it < 8; ++it) {
            const int i = base + it * 256 + t;
            const float4 v0 = reinterpret_cast<const float4*>(A + (size_t)i * 8)[0];
            const float4 v1 = reinterpret_cast<const float4*>(A + (size_t)i * 8)[1];
            bf16x8 w;
            w[0]=f2bf(v0.x); w[1]=f2bf(v0.y); w[2]=f2bf(v0.z); w[3]=f2bf(v0.w);
            w[4]=f2bf(v1.x); w[5]=f2bf(v1.y); w[6]=f2bf(v1.z); w[7]=f2bf(v1.w);
            *reinterpret_cast<bf16x8*>(Ab + (size_t)i * 8) = w;
        }
    }
}

// ------- 4-wave staged 128x128 tile machinery (fallback paths) -------

__device__ __forceinline__ void stage_tiles_g(const short* __restrict__ A,
                                              const short* __restrict__ B,
                                              int m0, int n0, int k0,
                                              int lda, int ldb,
                                              short* As, short* Bs,
                                              int wave, int lane)
{
    #pragma unroll
    for (int t = 0; t < 2; ++t) {
        const int c  = (wave * 2 + t) * 64 + lane;
        const int r  = c >> 2;
        const int g  = c & 3;
        const int sg = g ^ ((r >> 1) & 3);
        gload16(A + (size_t)(m0 + r) * lda + k0 + sg * 8, As + (wave * 2 + t) * 512);
        gload16(B + (size_t)(n0 + r) * ldb + k0 + sg * 8, Bs + (wave * 2 + t) * 512);
    }
}

template<int KSTEPS>
__device__ __forceinline__ void gemm_tile_g(const short* __restrict__ A,
                                            const short* __restrict__ B,
                                            int m0, int n0, int kbase,
                                            int lda, int ldb, int tid,
                                            short (*Sm)[2][4096],
                                            f32x4 acc[4][4])
{
    const int lane = tid & 63;
    const int wave = tid >> 6;
    const int rl   = lane & 15;
    const int g_rd = lane >> 4;
    const int wr   = wave >> 1;
    const int wc   = wave & 1;

    stage_tiles_g(A, B, m0, n0, kbase, lda, ldb, &Sm[0][0][0], &Sm[0][1][0], wave, lane);
    if (KSTEPS > 1)
        stage_tiles_g(A, B, m0, n0, kbase + BK, lda, ldb,
                      &Sm[1][0][0], &Sm[1][1][0], wave, lane);
    if (KSTEPS > 1) { VMCNT4; } else { VMCNT0; }
    SBAR;

    #pragma unroll
    for (int kt = 0; kt < KSTEPS; ++kt) {
        const int cur = kt % 3;
        if (kt + 2 < KSTEPS)
            stage_tiles_g(A, B, m0, n0, kbase + (kt + 2) * BK, lda, ldb,
                          &Sm[(kt + 2) % 3][0][0], &Sm[(kt + 2) % 3][1][0], wave, lane);

        bf16x8 af[4], bfr[4];
        #pragma unroll
        for (int mi = 0; mi < 4; ++mi) {
            const int r  = wr * 64 + mi * 16 + rl;
            const int sg = g_rd ^ ((r >> 1) & 3);
            af[mi] = *reinterpret_cast<const bf16x8*>(&Sm[cur][0][r * BK + sg * 8]);
        }
        #pragma unroll
        for (int ni = 0; ni < 4; ++ni) {
            const int r  = wc * 64 + ni * 16 + rl;
            const int sg = g_rd ^ ((r >> 1) & 3);
            bfr[ni] = *reinterpret_cast<const bf16x8*>(&Sm[cur][1][r * BK + sg * 8]);
        }
        __builtin_amdgcn_s_setprio(1);
        #pragma unroll
        for (int mi = 0; mi < 4; ++mi)
            #pragma unroll
            for (int ni = 0; ni < 4; ++ni)
                acc[mi][ni] = __builtin_amdgcn_mfma_f32_16x16x32_bf16(
                    af[mi], bfr[ni], acc[mi][ni], 0, 0, 0);
        __builtin_amdgcn_s_setprio(0);

        if (kt + 1 < KSTEPS) {
            if (kt + 2 < KSTEPS) { VMCNT4; } else { VMCNT0; }
            SBAR;
        }
    }
}

// ------- 8-wave (512-thread) staged 128x128 tile: per-wave 64x32, acc[4][2] -------
// Stage = 2 gload16/thread; counted wait vmcnt(2); LDS 16 KB/buf x 3 = 48 KB.

__device__ __forceinline__ void stage_g512(const short* __restrict__ A,
                                           const short* __restrict__ B,
                                           int m0, int n0, int k0,
                                           int lda, int ldb,
                                           short* buf, int wave, int lane)
{
    const int c  = wave * 64 + lane;   // 0..511
    const int r  = c >> 2;              // 0..127
    const int g  = c & 3;
    const int sg = g ^ ((r >> 1) & 3);
    gload16(A + (size_t)(m0 + r) * lda + k0 + sg * 8, buf + wave * 512);
    gload16(B + (size_t)(n0 + r) * ldb + k0 + sg * 8, buf + 4096 + wave * 512);
}

template<int KSTEPS>
__device__ __forceinline__ void gemm_tile_512g(const short* __restrict__ A,
                                               const short* __restrict__ B,
                                               int m0, int n0, int kbase,
                                               int lda, int ldb, int tid,
                                               short (*Sm)[8192],
                                               f32x4 acc[4][2])
{
    const int lane = tid & 63;
    const int wave = tid >> 6;        // 0..7
    const int rl   = lane & 15;
    const int g_rd = lane >> 4;
    const int wr   = wave >> 2;       // 0..1
    const int wc   = wave & 3;        // 0..3

    stage_g512(A, B, m0, n0, kbase, lda, ldb, Sm[0], wave, lane);
    if (KSTEPS > 1)
        stage_g512(A, B, m0, n0, kbase + BK, lda, ldb, Sm[1], wave, lane);
    if (KSTEPS > 1) { VMCNT2; } else { VMCNT0; }
    SBAR;

    #pragma unroll
    for (int kt = 0; kt < KSTEPS; ++kt) {
        const int cur = kt % 3;
        if (kt + 2 < KSTEPS)
            stage_g512(A, B, m0, n0, kbase + (kt + 2) * BK, lda, ldb,
                       Sm[(kt + 2) % 3], wave, lane);

        bf16x8 af[4], bfr[2];
        #pragma unroll
        for (int mi = 0; mi < 4; ++mi) {
            const int rr = wr * 64 + mi * 16 + rl;
            const int sg = g_rd ^ ((rr >> 1) & 3);
            af[mi] = *reinterpret_cast<const bf16x8*>(&Sm[cur][rr * BK + sg * 8]);
        }
        #pragma unroll
        for (int ni = 0; ni < 2; ++ni) {
            const int rr = wc * 32 + ni * 16 + rl;
            const int sg = g_rd ^ ((rr >> 1) & 3);
            bfr[ni] = *reinterpret_cast<const bf16x8*>(&Sm[cur][4096 + rr * BK + sg * 8]);
        }
        __builtin_amdgcn_s_setprio(1);
        #pragma unroll
        for (int mi = 0; mi < 4; ++mi)
            #pragma unroll
            for (int ni = 0; ni < 2; ++ni)
                acc[mi][ni] = __builtin_amdgcn_mfma_f32_16x16x32_bf16(
                    af[mi], bfr[ni], acc[mi][ni], 0, 0, 0);
        __builtin_amdgcn_s_setprio(0);

        if (kt + 1 < KSTEPS) {
            if (kt + 2 < KSTEPS) { VMCNT2; } else { VMCNT0; }
            SBAR;
        }
    }
}

// ---------------- Gram path (512-thread / 8-wave) ----------------

template<int STEPS>
__global__ __launch_bounds__(512, 4) void gemm_G(const short* __restrict__ Bt,
                                                 float* __restrict__ Gp)
{
    __shared__ __align__(16) short Sm[3][8192];   // 48 KB
    const int tid = threadIdx.x;
    const int m0 = blockIdx.y * BM, n0 = blockIdx.x * BN;
    const int z  = blockIdx.z;
    f32x4 acc[4][2] = {};
    gemm_tile_512g<STEPS>(Bt, Bt, m0, n0, z * (STEPS * BK),
                          M_TOT, M_TOT, tid, Sm, acc);

    float* dst = Gp + (size_t)z * (C_TOT * C_TOT);
    const int lane = tid & 63, rl = lane & 15;
    const int wave = tid >> 6, wr = wave >> 2, wc = wave & 3;
    #pragma unroll
    for (int mi = 0; mi < 4; ++mi)
        #pragma unroll
        for (int i = 0; i < 4; ++i) {
            const int m = m0 + wr * 64 + mi * 16 + (lane >> 4) * 4 + i;
            #pragma unroll
            for (int ni = 0; ni < 2; ++ni)
                dst[m * C_TOT + n0 + wc * 32 + ni * 16 + rl] = acc[mi][ni][i];
        }
}

__global__ __launch_bounds__(256) void g_reduce(const float* __restrict__ Gp,
                                                short* __restrict__ Gb,
                                                int nchunks)
{
    const int i4 = blockIdx.x * 256 + threadIdx.x;
    float4 s = make_float4(0.f, 0.f, 0.f, 0.f);
    for (int z = 0; z < nchunks; ++z) {
        const float4 v = reinterpret_cast<const float4*>(
            Gp + (size_t)z * (C_TOT * C_TOT))[i4];
        s.x += v.x; s.y += v.y; s.z += v.z; s.w += v.w;
    }
    short4 o;
    o.x = f2bf(s.x); o.y = f2bf(s.y); o.z = f2bf(s.z); o.w = f2bf(s.w);
    reinterpret_cast<short4*>(Gb)[i4] = o;
}

// P[m] += sum over quadrant (ci, cj); 512-thread / 8-wave
__global__ __launch_bounds__(512, 4) void penalty_q(const short* __restrict__ Ab,
                                                    const short* __restrict__ Gb,
                                                    float* __restrict__ P)
{
    __shared__ __align__(16) short Sm[3][8192];
    const int tid = threadIdx.x;
    const int m0 = blockIdx.x * BM;
    const int ci = blockIdx.y & 1, cj = blockIdx.y >> 1;
    const int lane = tid & 63, rl = lane & 15;
    const int wave = tid >> 6, wr = wave >> 2, wc = wave & 3;

    f32x4 acc[4][2] = {};
    gemm_tile_512g<4>(Ab, Gb + (size_t)(cj * BM) * C_TOT, m0, 0, ci * BM,
                      C_TOT, C_TOT, tid, Sm, acc);

    #pragma unroll
    for (int mi = 0; mi < 4; ++mi)
        #pragma unroll
        for (int i = 0; i < 4; ++i) {
            const int m = m0 + wr * 64 + mi * 16 + (lane >> 4) * 4 + i;
            float s = 0.0f;
            #pragma unroll
            for (int ni = 0; ni < 2; ++ni) {
                const int cp = cj * BM + wc * 32 + ni * 16 + rl;
                s += acc[mi][ni][i] * bf2f(Ab[(size_t)m * C_TOT + cp]);
            }
            s += __shfl_xor(s, 1);
            s += __shfl_xor(s, 2);
            s += __shfl_xor(s, 4);
            s += __shfl_xor(s, 8);
            if (rl == 0) atomicAdd(&P[m], s);
        }
}

// ------- output GEMM: 128x128 tile, 512 threads / 8 waves, 3 blocks/CU -------
// (round-15 config: best measured, 6 waves/SIMD + 3-buffer counted-vmcnt)

__global__ __launch_bounds__(512, 6) void gemm_out(const short* __restrict__ Ab,
                                                   const short* __restrict__ Bb,
                                                   const float* __restrict__ P,
                                                   float* __restrict__ out)
{
    __shared__ __align__(16) short Sm[3][8192];   // 48 KB
    const int tid = threadIdx.x;
    const int lane = tid & 63, rl = lane & 15;
    const int wave = tid >> 6;            // 0..7
    const int wr   = wave >> 2;           // 0..1  (m half)
    const int wc   = wave & 3;            // 0..3  (n quarter)

    // bijective chunked XCD swizzle (m204): 2500 blocks, 8 XCDs (q=312, r=4)
    const int nwg = NTILE * NTILE, q = nwg >> 3, r = nwg & 7;
    const int orig = blockIdx.x;
    const int xcd = orig & 7, idx = orig >> 3;
    const int wg = (xcd < r ? xcd * (q + 1) : r * (q + 1) + (xcd - r) * q) + idx;
    const int m0 = (wg / NTILE) * BM;
    const int n0 = (wg % NTILE) * BN;

    f32x4 acc[4][2] = {};
    gemm_tile_512g<8>(Ab, Bb, m0, n0, 0, C_TOT, C_TOT, tid, Sm, acc);

    float rs[2];
    #pragma unroll
    for (int ni = 0; ni < 2; ++ni)
        rs[ni] = rsqrtf(P[n0 + wc * 32 + ni * 16 + rl]);

    SBAR;   // all waves done reading Sm before epilogue scratch reuse

    // wave-private 16x36 f32 scratch (8 waves x 2304 B = 18 KB, aliased on Sm)
    float* Es = reinterpret_cast<float*>(Sm) + wave * 576;
    #pragma unroll
    for (int mi = 0; mi < 4; ++mi) {
        #pragma unroll
        for (int ni = 0; ni < 2; ++ni)
            #pragma unroll
            for (int i = 0; i < 4; ++i)
                Es[((lane >> 4) * 4 + i) * 36 + ni * 16 + rl] = acc[mi][ni][i] * rs[ni];
        #pragma unroll
        for (int it = 0; it < 2; ++it) {
            const int f   = it * 64 + lane;   // 0..127
            const int row = f >> 3;           // 0..15
            const int c4  = f & 7;            // float4 column 0..7
            const f32x4 v = *reinterpret_cast<const f32x4*>(&Es[row * 36 + c4 * 4]);
            const int m = m0 + wr * 64 + mi * 16 + row;
            __builtin_nontemporal_store(v, reinterpret_cast<f32x4*>(
                &out[(size_t)m * M_TOT + n0 + wc * 32 + c4 * 4]));
        }
    }
}

// ---------------- mid fallback: two-GEMM (128^2, staged, 4-wave) ----------------

__global__ __launch_bounds__(256) void convert_ab(const float* __restrict__ A,
                                                  const float* __restrict__ Bm,
                                                  short* __restrict__ Ab,
                                                  short* __restrict__ Bb)
{
    const int n8 = M_TOT * C_TOT / 8;
    for (int i = blockIdx.x * blockDim.x + threadIdx.x; i < 2 * n8;
         i += gridDim.x * blockDim.x) {
        const float* s = (i < n8) ? (A + (size_t)i * 8) : (Bm + (size_t)(i - n8) * 8);
        short* d       = (i < n8) ? (Ab + (size_t)i * 8) : (Bb + (size_t)(i - n8) * 8);
        const float4 v0 = reinterpret_cast<const float4*>(s)[0];
        const float4 v1 = reinterpret_cast<const float4*>(s)[1];
        bf16x8 w;
        w[0]=f2bf(v0.x); w[1]=f2bf(v0.y); w[2]=f2bf(v0.z); w[3]=f2bf(v0.w);
        w[4]=f2bf(v1.x); w[5]=f2bf(v1.y); w[6]=f2bf(v1.z); w[7]=f2bf(v1.w);
        *reinterpret_cast<bf16x8*>(d) = w;
    }
}

__global__ __launch_bounds__(256) void gemm_penalty(const short* __restrict__ Ab,
                                                    const short* __restrict__ Bb,
                                                    float* __restrict__ P)
{
    __shared__ __align__(16) short Sm[3][2][4096];
    const int tid = threadIdx.x;
    const int m0 = blockIdx.y * BM, n0 = blockIdx.x * BN;
    f32x4 acc[4][4] = {};
    gemm_tile_g<8>(Ab, Bb, m0, n0, 0, C_TOT, C_TOT, tid, Sm, acc);

    const int lane = tid & 63, rl = lane & 15;
    const int wave = tid >> 6, wr = wave >> 1;
    #pragma unroll
    for (int mi = 0; mi < 4; ++mi) {
        #pragma unroll
        for (int i = 0; i < 4; ++i) {
            const int m = m0 + wr * 64 + mi * 16 + (lane >> 4) * 4 + i;
            float s = 0.0f;
            #pragma unroll
            for (int ni = 0; ni < 4; ++ni) {
                const float v = acc[mi][ni][i];
                s += v * v;
            }
            s += __shfl_xor(s, 1);
            s += __shfl_xor(s, 2);
            s += __shfl_xor(s, 4);
            s += __shfl_xor(s, 8);
            if (rl == 0) atomicAdd(&P[m], s);
        }
    }
}

__global__ __launch_bounds__(256) void gemm_out_plain(const short* __restrict__ Ab,
                                                      const short* __restrict__ Bb,
                                                      const float* __restrict__ P,
                                                      float* __restrict__ out)
{
    __shared__ __align__(16) short Sm[3][2][4096];
    const int tid = threadIdx.x;
    const int lane = tid & 63, rl = lane & 15;
    const int wave = tid >> 6, wr = wave >> 1, wc = wave & 1;
    const int m0 = blockIdx.y * BM, n0 = blockIdx.x * BN;

    f32x4 acc[4][4] = {};
    gemm_tile_g<8>(Ab, Bb, m0, n0, 0, C_TOT, C_TOT, tid, Sm, acc);

    float rs[4];
    #pragma unroll
    for (int ni = 0; ni < 4; ++ni)
        rs[ni] = rsqrtf(P[n0 + wc * 64 + ni * 16 + rl]);

    SBAR;

    float* Es = reinterpret_cast<float*>(Sm) + wave * 1088;
    #pragma unroll
    for (int mi = 0; mi < 4; ++mi) {
        #pragma unroll
        for (int ni = 0; ni < 4; ++ni)
            #pragma unroll
            for (int i = 0; i < 4; ++i)
                Es[((lane >> 4) * 4 + i) * 68 + ni * 16 + rl] = acc[mi][ni][i] * rs[ni];
        #pragma unroll
        for (int it = 0; it < 4; ++it) {
            const int f   = it * 64 + lane;
            const int row = f >> 4;
            const int c4  = f & 15;
            const float4 v = *reinterpret_cast<const float4*>(&Es[row * 68 + c4 * 4]);
            const int m = m0 + wr * 64 + mi * 16 + row;
            *reinterpret_cast<float4*>(&out[(size_t)m * M_TOT + n0 + wc * 64 + c4 * 4]) = v;
        }
    }
}

// ---------------- final fallback (round-1) ----------------

__global__ __launch_bounds__(256) void corr_gemm(const float* __restrict__ A,
                                                 const float* __restrict__ Bm,
                                                 float* __restrict__ out,
                                                 float* __restrict__ penalty)
{
    __shared__ short As[BM * BK];
    __shared__ short Bs[BN * BK];

    const int tid  = threadIdx.x;
    const int lane = tid & 63;
    const int wave = tid >> 6;
    const int wr   = wave >> 1;
    const int wc   = wave & 1;
    const int m0   = blockIdx.y * BM;
    const int n0   = blockIdx.x * BN;
    const int g_rd = lane >> 4;
    const int rl   = lane & 15;

    f32x4 acc[4][4] = {};

    for (int k0 = 0; k0 < C_TOT; k0 += BK) {
        #pragma unroll
        for (int half = 0; half < 2; ++half) {
            const int cc = tid + half * 256;
            const int r  = cc >> 2;
            const int g  = cc & 3;
            const int sg = g ^ ((r >> 1) & 3);

            const float4* pa = reinterpret_cast<const float4*>(
                A + (size_t)(m0 + r) * C_TOT + k0 + g * 8);
            float4 a0 = pa[0], a1 = pa[1];
            bf16x8 wa;
            wa[0]=f2bf(a0.x); wa[1]=f2bf(a0.y); wa[2]=f2bf(a0.z); wa[3]=f2bf(a0.w);
            wa[4]=f2bf(a1.x); wa[5]=f2bf(a1.y); wa[6]=f2bf(a1.z); wa[7]=f2bf(a1.w);
            *reinterpret_cast<bf16x8*>(&As[r * BK + sg * 8]) = wa;

            const float4* pb = reinterpret_cast<const float4*>(
                Bm + (size_t)(n0 + r) * C_TOT + k0 + g * 8);
            float4 b0 = pb[0], b1 = pb[1];
            bf16x8 wb;
            wb[0]=f2bf(b0.x); wb[1]=f2bf(b0.y); wb[2]=f2bf(b0.z); wb[3]=f2bf(b0.w);
            wb[4]=f2bf(b1.x); wb[5]=f2bf(b1.y); wb[6]=f2bf(b1.z); wb[7]=f2bf(b1.w);
            *reinterpret_cast<bf16x8*>(&Bs[r * BK + sg * 8]) = wb;
        }
        __syncthreads();

        bf16x8 af[4], bfr[4];
        #pragma unroll
        for (int mi = 0; mi < 4; ++mi) {
            const int r  = wr * 64 + mi * 16 + rl;
            const int sg = g_rd ^ ((r >> 1) & 3);
            af[mi] = *reinterpret_cast<const bf16x8*>(&As[r * BK + sg * 8]);
        }
        #pragma unroll
        for (int ni = 0; ni < 4; ++ni) {
            const int r  = wc * 64 + ni * 16 + rl;
            const int sg = g_rd ^ ((r >> 1) & 3);
            bfr[ni] = *reinterpret_cast<const bf16x8*>(&Bs[r * BK + sg * 8]);
        }
        #pragma unroll
        for (int mi = 0; mi < 4; ++mi)
            #pragma unroll
            for (int ni = 0; ni < 4; ++ni)
                acc[mi][ni] = __builtin_amdgcn_mfma_f32_16x16x32_bf16(
                    af[mi], bfr[ni], acc[mi][ni], 0, 0, 0);
        __syncthreads();
    }

    const float inv_c = 1.0f / (float)C_TOT;
    #pragma unroll
    for (int mi = 0; mi < 4; ++mi) {
        #pragma unroll
        for (int i = 0; i < 4; ++i) {
            const int m = m0 + wr * 64 + mi * 16 + (lane >> 4) * 4 + i;
            float s = 0.0f;
            #pragma unroll
            for (int ni = 0; ni < 4; ++ni) {
                const float v = acc[mi][ni][i] * inv_c;
                out[(size_t)m * M_TOT + n0 + wc * 64 + ni * 16 + rl] = v;
                s += v * v;
            }
            s += __shfl_xor(s, 1);
            s += __shfl_xor(s, 2);
            s += __shfl_xor(s, 4);
            s += __shfl_xor(s, 8);
            if (rl == 0) atomicAdd(&penalty[m], s);
        }
    }
}

__global__ __launch_bounds__(256) void scale_k(float* __restrict__ out,
                                               const float* __restrict__ penalty)
{
    const unsigned cols4 = M_TOT / 4;
    const unsigned total = (unsigned)M_TOT * cols4;
    float4* o4 = reinterpret_cast<float4*>(out);
    const float4* p4 = reinterpret_cast<const float4*>(penalty);
    for (unsigned idx = blockIdx.x * blockDim.x + threadIdx.x; idx < total;
         idx += gridDim.x * blockDim.x) {
        const unsigned n4 = idx % cols4;
        const float4 p = p4[n4];
        float4 v = o4[idx];
        v.x *= rsqrtf(p.x);
        v.y *= rsqrtf(p.y);
        v.z *= rsqrtf(p.z);
        v.w *= rsqrtf(p.w);
        o4[idx] = v;
    }
}

// ---------------- launch ----------------

extern "C" void kernel_launch(void* const* d_in, const int* in_sizes, int n_in,
                              void* d_out, int out_size, void* d_ws, size_t ws_size,
                              hipStream_t stream) {
    const float* A = (const float*)d_in[0];
    const float* B = (const float*)d_in[1];
    float* out     = (float*)d_out;

    const size_t mat_sh = (size_t)M_TOT * C_TOT;
    const size_t sz_ab  = mat_sh * sizeof(short);
    const size_t sz_gb  = (size_t)C_TOT * C_TOT * sizeof(short);
    const size_t sz_p   = (size_t)M_TOT * sizeof(float);
    const size_t sz_gq  = (size_t)C_TOT * C_TOT * sizeof(float);
    const size_t base_need = 3 * sz_ab + sz_gb + sz_p;
    const size_t need_f40  = base_need + 40 * sz_gq;           // ~20.5 MB
    const size_t need_f20  = base_need + 20 * sz_gq;           // ~15.3 MB
    const size_t need_mid  = 2 * sz_ab + sz_p;                 // ~6.6 MB

    dim3 grid2(NTILE, NTILE);

    if (ws_size >= need_f20) {
        short* Ab = (short*)d_ws;
        short* Bb = Ab + mat_sh;
        short* Bt = Bb + mat_sh;
        short* Gb = Bt + mat_sh;
        float* P  = (float*)((char*)d_ws + 3 * sz_ab + sz_gb);
        float* Gp = (float*)((char*)d_ws + 3 * sz_ab + sz_gb + sz_p);

        prep<<<500, 256, 0, stream>>>(A, B, Ab, Bb, Bt, P);
        if (ws_size >= need_f40) {
            gemm_G<5><<<dim3(2, 2, 40), 512, 0, stream>>>(Bt, Gp);
            g_reduce<<<64, 256, 0, stream>>>(Gp, Gb, 40);
        } else {
            gemm_G<10><<<dim3(2, 2, 20), 512, 0, stream>>>(Bt, Gp);
            g_reduce<<<64, 256, 0, stream>>>(Gp, Gb, 20);
        }
        penalty_q<<<dim3(NTILE, 4), 512, 0, stream>>>(Ab, Gb, P);
        gemm_out<<<NTILE * NTILE, 512, 0, stream>>>(Ab, Bb, P, out);
    } else if (ws_size >= need_mid) {
        short* Ab = (short*)d_ws;
        short* Bb = Ab + mat_sh;
        float* P  = (float*)(Bb + mat_sh);

        (void)hipMemsetAsync(P, 0, sz_p, stream);
        convert_ab<<<1600, 256, 0, stream>>>(A, B, Ab, Bb);
        gemm_penalty<<<grid2, dim3(256), 0, stream>>>(Ab, Bb, P);
        gemm_out_plain<<<grid2, dim3(256), 0, stream>>>(Ab, Bb, P, out);
    } else {
        float* penalty = (float*)d_ws;
        (void)hipMemsetAsync(penalty, 0, sz_p, stream);
        corr_gemm<<<grid2, dim3(256), 0, stream>>>(A, B, out, penalty);
        scale_k<<<2048, 256, 0, stream>>>(out, penalty);
    }
}